// Round 3
// baseline (328.223 us; speedup 1.0000x reference)
//
#include <hip/hip_runtime.h>
#include <hip/hip_bf16.h>

// Distance-kernel attention, B=1, L=2048, D=768, H=12, dk=64.
// out0 [L,D] fp32 = context @ Wo^T + bo ; out1 [L,L] fp32 = mean_h attn_weights.
// All matmuls via mfma_f32_16x16x32_bf16 in "NT" form (both operands K-contiguous,
// identical lane->k mapping on A and B => result independent of HW K-permutation).
// K/V per head (256KB) is L2-resident: attention passes load MFMA fragments
// DIRECTLY from global (no LDS staging, no barriers in the j-loop).

typedef __bf16 bf16_t;
typedef bf16_t bf16x8 __attribute__((ext_vector_type(8)));
typedef float f32x4 __attribute__((ext_vector_type(4)));

#define L_SEQ 2048
#define DIM 768
#define NH 12
#define DKH 64
#define JSPLIT 4   // j-chunks in maxdist pass

__device__ __forceinline__ bf16x8 ldg8(const bf16_t* p) { return *(const bf16x8*)p; }
__device__ __forceinline__ f32x4 mfma16(bf16x8 a, bf16x8 b, f32x4 c_) {
  return __builtin_amdgcn_mfma_f32_16x16x32_bf16(a, b, c_, 0, 0, 0);
}

// ---- LDS-staged GEMM helpers (used only by the K=768 projections) -------

__device__ __forceinline__ void stage64(const bf16_t* __restrict__ src, int row_stride,
                                        bf16_t (*dst)[72], int tid) {
#pragma unroll
  for (int c = 0; c < 2; ++c) {
    int chunk = tid + c * 256;
    int row = chunk >> 3;
    int col = (chunk & 7) * 8;
    *(bf16x8*)&dst[row][col] = *(const bf16x8*)&src[(size_t)row * row_stride + col];
  }
}

__device__ __forceinline__ void mfma_nt64(bf16_t (*As)[72], bf16_t (*Bs)[72],
                                          int wid, int lane, f32x4 acc[4]) {
#pragma unroll
  for (int ks = 0; ks < 2; ++ks) {
    bf16x8 a = *(const bf16x8*)&As[wid * 16 + (lane & 15)][ks * 32 + (lane >> 4) * 8];
#pragma unroll
    for (int nt = 0; nt < 4; ++nt) {
      bf16x8 b = *(const bf16x8*)&Bs[nt * 16 + (lane & 15)][ks * 32 + (lane >> 4) * 8];
      acc[nt] = mfma16(a, b, acc[nt]);
    }
  }
}

// ---- kernels ------------------------------------------------------------

__global__ void cast_x(const float* __restrict__ in, bf16_t* __restrict__ out, int n4) {
  int i = blockIdx.x * 256 + threadIdx.x;
  if (i >= n4) return;
  float4 v = ((const float4*)in)[i];
  bf16_t* o = out + (size_t)i * 4;
  o[0] = (bf16_t)v.x; o[1] = (bf16_t)v.y; o[2] = (bf16_t)v.z; o[3] = (bf16_t)v.w;
}

__global__ void cast_w4(const float* __restrict__ w0, const float* __restrict__ w1,
                        const float* __restrict__ w2, const float* __restrict__ w3,
                        bf16_t* __restrict__ o0, bf16_t* __restrict__ o1,
                        bf16_t* __restrict__ o2, bf16_t* __restrict__ o3, int n4) {
  int i = blockIdx.x * 256 + threadIdx.x;
  if (i >= n4) return;
  const float* in = blockIdx.y == 0 ? w0 : blockIdx.y == 1 ? w1 : blockIdx.y == 2 ? w2 : w3;
  bf16_t* out = blockIdx.y == 0 ? o0 : blockIdx.y == 1 ? o1 : blockIdx.y == 2 ? o2 : o3;
  float4 v = ((const float4*)in)[i];
  bf16_t* o = out + (size_t)i * 4;
  o[0] = (bf16_t)v.x; o[1] = (bf16_t)v.y; o[2] = (bf16_t)v.z; o[3] = (bf16_t)v.w;
}

// Generic NT GEMM: out[m,n] = sum_k A[m,k]*B[n,k] + bias[n].
// MODE 0: q/k — bf16 head-split out[h][m][d], plus row sum-of-squares -> norm[h*L+m]
// MODE 1: v  — bf16 transposed out vt[(h*64+d)][m]
// MODE 2: fp32 row-major out[m*N + n]  (final projection)
template <int MODE>
__global__ __launch_bounds__(256) void gemm_nt(const bf16_t* __restrict__ A,
                                               const bf16_t* __restrict__ B,
                                               const float* __restrict__ bias,
                                               void* __restrict__ outp,
                                               float* __restrict__ norm,
                                               int M, int N, int K) {
  __shared__ bf16_t As[64][72];
  __shared__ bf16_t Bs[64][72];
  const int tid = threadIdx.x, wid = tid >> 6, lane = tid & 63;
  const int m0 = blockIdx.y * 64, n0 = blockIdx.x * 64;
  f32x4 acc[4] = {};
  for (int kk = 0; kk < K; kk += 64) {
    __syncthreads();
    stage64(A + (size_t)m0 * K + kk, K, As, tid);
    stage64(B + (size_t)n0 * K + kk, K, Bs, tid);
    __syncthreads();
    mfma_nt64(As, Bs, wid, lane, acc);
  }
  const int r0 = wid * 16 + ((lane >> 4) << 2);
  float ss[4] = {0.f, 0.f, 0.f, 0.f};
#pragma unroll
  for (int nt = 0; nt < 4; ++nt) {
    int cc = n0 + nt * 16 + (lane & 15);
    float bv = bias[cc];
#pragma unroll
    for (int r = 0; r < 4; ++r) {
      int mm = m0 + r0 + r;
      float val = acc[nt][r] + bv;
      if (MODE == 0) {
        bf16_t* out = (bf16_t*)outp;
        int h = cc >> 6, d = cc & 63;
        out[((size_t)h * M + mm) * 64 + d] = (bf16_t)val;
        ss[r] = fmaf(val, val, ss[r]);
      } else if (MODE == 1) {
        bf16_t* out = (bf16_t*)outp;
        out[(size_t)cc * M + mm] = (bf16_t)val;   // vt[h*64+d][m]
      } else {
        float* out = (float*)outp;
        out[(size_t)mm * N + cc] = val;
      }
    }
  }
  if (MODE == 0) {
#pragma unroll
    for (int s = 1; s < 16; s <<= 1)
#pragma unroll
      for (int r = 0; r < 4; ++r) ss[r] += __shfl_xor(ss[r], s);
    if ((lane & 15) == 0) {
      int h = n0 >> 6;
#pragma unroll
      for (int r = 0; r < 4; ++r) norm[h * M + m0 + r0 + r] = ss[r];
    }
  }
}

// Pass 1: per-block max of dist_sq. grid (i-tiles, JSPLIT, NH). No LDS staging.
__global__ __launch_bounds__(256, 4) void maxdist(const bf16_t* __restrict__ q,
                                                  const bf16_t* __restrict__ k,
                                                  const float* __restrict__ qn,
                                                  const float* __restrict__ kn,
                                                  float* __restrict__ blockmax) {
  __shared__ float wmax[4];
  const int it = blockIdx.x, jcb = blockIdx.y, h = blockIdx.z;
  const int tid = threadIdx.x, wid = tid >> 6, lane = tid & 63;
  const int c = lane & 15, hi = lane >> 4;
  const int iw0 = it * 64 + wid * 16;
  const bf16_t* qrow = q + ((size_t)h * L_SEQ + iw0 + c) * DKH;
  bf16x8 qa0 = ldg8(qrow + hi * 8);
  bf16x8 qa1 = ldg8(qrow + 32 + hi * 8);
  float qnr[4];
#pragma unroll
  for (int r = 0; r < 4; ++r) qnr[r] = qn[h * L_SEQ + iw0 + hi * 4 + r];
  float m = 0.f;
  for (int t = 0; t < L_SEQ / 64 / JSPLIT; ++t) {
    const int j0 = jcb * (L_SEQ / JSPLIT) + t * 64;
    const bf16_t* kbase = k + ((size_t)h * L_SEQ + j0) * DKH;
    f32x4 acc[4] = {};
#pragma unroll
    for (int nt = 0; nt < 4; ++nt) {
      bf16x8 kb0 = ldg8(kbase + (size_t)(nt * 16 + c) * DKH + hi * 8);
      bf16x8 kb1 = ldg8(kbase + (size_t)(nt * 16 + c) * DKH + 32 + hi * 8);
      acc[nt] = mfma16(qa0, kb0, acc[nt]);
      acc[nt] = mfma16(qa1, kb1, acc[nt]);
    }
#pragma unroll
    for (int nt = 0; nt < 4; ++nt) {
      float knc = kn[h * L_SEQ + j0 + nt * 16 + c];
#pragma unroll
      for (int r = 0; r < 4; ++r)
        m = fmaxf(m, fmaxf(qnr[r] + knc - 2.f * acc[nt][r], 0.f));
    }
  }
#pragma unroll
  for (int s = 1; s < 64; s <<= 1) m = fmaxf(m, __shfl_xor(m, s));
  if (lane == 0) wmax[wid] = m;
  __syncthreads();
  if (tid == 0) {
    float bm = fmaxf(fmaxf(wmax[0], wmax[1]), fmaxf(wmax[2], wmax[3]));
    blockmax[(h * JSPLIT + jcb) * (L_SEQ / 64) + it] = bm * (1.f / 64.f);
  }
}

__global__ void reduce_dmax(const float* __restrict__ blockmax, float* __restrict__ dmax) {
  __shared__ float wm[2];
  const int h = blockIdx.x, tid = threadIdx.x, lane = tid & 63, wid = tid >> 6;
  float m = blockmax[h * 128 + tid];
#pragma unroll
  for (int s = 1; s < 64; s <<= 1) m = fmaxf(m, __shfl_xor(m, s));
  if (lane == 0) wm[wid] = m;
  __syncthreads();
  if (tid == 0) dmax[h] = fmaxf(wm[0], wm[1]);
}

// Pass 2 (fused): online denominator + unnormalized context + normalize.
// 8 waves: 4 row-groups x 2 j-halves; barrier-free j-loop; one final barrier
// to merge the two j-half partials through LDS. W tile per-wave, XOR-swizzled.
__global__ __launch_bounds__(512, 4) void fusedctx(const bf16_t* __restrict__ q,
                                                   const bf16_t* __restrict__ k,
                                                   const bf16_t* __restrict__ vt,
                                                   const float* __restrict__ qn,
                                                   const float* __restrict__ kn,
                                                   const float* __restrict__ dmax,
                                                   const float* __restrict__ theta,
                                                   float* __restrict__ den,
                                                   bf16_t* __restrict__ ctx) {
  __shared__ bf16_t Wl[8][16 * 64];   // per-wave 16x64, 128B rows, XOR-swizzled
  __shared__ float ctxP[4][16][64];   // j-half-1 context partials
  __shared__ float denP[8][64];       // per-wave denominator partials
  const int h = blockIdx.y, i0 = blockIdx.x * 64;
  const int tid = threadIdx.x, wid = tid >> 6, lane = tid & 63;
  const int wr = wid & 3, jc = wid >> 2;
  const int c = lane & 15, hi = lane >> 4;
  const int iw0 = i0 + wr * 16;
  const float sc = __expf(theta[h]) * (1.f / 64.f) / (dmax[h] + 1e-6f);
  const bf16_t* qrow = q + ((size_t)h * L_SEQ + iw0 + c) * DKH;
  bf16x8 qa0 = ldg8(qrow + hi * 8);
  bf16x8 qa1 = ldg8(qrow + 32 + hi * 8);
  float qnr[4];
#pragma unroll
  for (int r = 0; r < 4; ++r) qnr[r] = qn[h * L_SEQ + iw0 + hi * 4 + r];
  float psum[4] = {0.f, 0.f, 0.f, 0.f};
  f32x4 cacc[4] = {};
  bf16_t* wb = &Wl[wid][0];
  for (int t = 0; t < L_SEQ / 2 / 64; ++t) {
    const int j0 = jc * (L_SEQ / 2) + t * 64;
    const bf16_t* kbase = k + ((size_t)h * L_SEQ + j0) * DKH;
    f32x4 acc[4] = {};
#pragma unroll
    for (int nt = 0; nt < 4; ++nt) {
      bf16x8 kb0 = ldg8(kbase + (size_t)(nt * 16 + c) * DKH + hi * 8);
      bf16x8 kb1 = ldg8(kbase + (size_t)(nt * 16 + c) * DKH + 32 + hi * 8);
      acc[nt] = mfma16(qa0, kb0, acc[nt]);
      acc[nt] = mfma16(qa1, kb1, acc[nt]);
    }
#pragma unroll
    for (int nt = 0; nt < 4; ++nt) {
      float knc = kn[h * L_SEQ + j0 + nt * 16 + c];
#pragma unroll
      for (int r = 0; r < 4; ++r) {
        float dist = fmaxf(qnr[r] + knc - 2.f * acc[nt][r], 0.f);
        float w = __expf(__expf(-sc * dist));   // in [1, e]
        psum[r] += w;
        int row = hi * 4 + r;
        int boff = row * 128 + ((nt * 32 + c * 2) ^ ((row & 7) << 4));
        *(bf16_t*)((char*)wb + boff) = (bf16_t)w;
      }
    }
    // PV: out m=i (A=W from per-wave LDS), n=d (B=vt rows, global/L2), k=j
    const bf16_t* vbase = vt + (size_t)h * DKH * L_SEQ + j0;
#pragma unroll
    for (int ks = 0; ks < 2; ++ks) {
      bf16x8 wa = *(const bf16x8*)((const char*)wb +
                   c * 128 + ((ks * 64 + hi * 16) ^ ((c & 7) << 4)));
#pragma unroll
      for (int nt = 0; nt < 4; ++nt) {
        bf16x8 vb = ldg8(vbase + (size_t)(nt * 16 + c) * L_SEQ + ks * 32 + hi * 8);
        cacc[nt] = mfma16(wa, vb, cacc[nt]);
      }
    }
  }
  // denominator: reduce across the 16-lane col group
#pragma unroll
  for (int s = 1; s < 16; s <<= 1)
#pragma unroll
    for (int r = 0; r < 4; ++r) psum[r] += __shfl_xor(psum[r], s);
  if (c == 0)
#pragma unroll
    for (int r = 0; r < 4; ++r) denP[wid][hi * 4 + r] = psum[r];
  if (jc == 1)
#pragma unroll
    for (int nt = 0; nt < 4; ++nt)
#pragma unroll
      for (int r = 0; r < 4; ++r) ctxP[wr][hi * 4 + r][nt * 16 + c] = cacc[nt][r];
  __syncthreads();
  if (jc == 0) {
    float inv[4];
#pragma unroll
    for (int r = 0; r < 4; ++r) {
      int row = hi * 4 + r;
      float d = denP[wr][row] + denP[wr + 4][row];
      inv[r] = 1.f / d;
      if (c == 0) den[h * L_SEQ + iw0 + row] = d;
    }
#pragma unroll
    for (int nt = 0; nt < 4; ++nt)
#pragma unroll
      for (int r = 0; r < 4; ++r) {
        float v = cacc[nt][r] + ctxP[wr][hi * 4 + r][nt * 16 + c];
        ctx[(size_t)(iw0 + hi * 4 + r) * DIM + h * 64 + nt * 16 + c] =
            (bf16_t)(v * inv[r]);
      }
  }
}

// Pass 3: out1[i][j] = mean over heads. LDS-free, barrier-free.
__global__ __launch_bounds__(256, 4) void attnmean(const bf16_t* __restrict__ q,
                                                   const bf16_t* __restrict__ k,
                                                   const float* __restrict__ qn,
                                                   const float* __restrict__ kn,
                                                   const float* __restrict__ dmax,
                                                   const float* __restrict__ theta,
                                                   const float* __restrict__ den,
                                                   float* __restrict__ out1) {
  const int i0 = blockIdx.y * 64, j0 = blockIdx.x * 64;
  const int tid = threadIdx.x, wid = tid >> 6, lane = tid & 63;
  const int c = lane & 15, hi = lane >> 4;
  const int iw0 = i0 + wid * 16;
  float macc[4][4] = {};
  for (int h = 0; h < NH; ++h) {
    const float sc = __expf(theta[h]) * (1.f / 64.f) / (dmax[h] + 1e-6f);
    const bf16_t* qrow = q + ((size_t)h * L_SEQ + iw0 + c) * DKH;
    bf16x8 qa0 = ldg8(qrow + hi * 8);
    bf16x8 qa1 = ldg8(qrow + 32 + hi * 8);
    const bf16_t* kbase = k + ((size_t)h * L_SEQ + j0) * DKH;
    f32x4 acc[4] = {};
#pragma unroll
    for (int nt = 0; nt < 4; ++nt) {
      bf16x8 kb0 = ldg8(kbase + (size_t)(nt * 16 + c) * DKH + hi * 8);
      bf16x8 kb1 = ldg8(kbase + (size_t)(nt * 16 + c) * DKH + 32 + hi * 8);
      acc[nt] = mfma16(qa0, kb0, acc[nt]);
      acc[nt] = mfma16(qa1, kb1, acc[nt]);
    }
    float qnr[4], invl[4];
#pragma unroll
    for (int r = 0; r < 4; ++r) {
      qnr[r] = qn[h * L_SEQ + iw0 + hi * 4 + r];
      invl[r] = 1.f / den[h * L_SEQ + iw0 + hi * 4 + r];
    }
#pragma unroll
    for (int nt = 0; nt < 4; ++nt) {
      float knc = kn[h * L_SEQ + j0 + nt * 16 + c];
#pragma unroll
      for (int r = 0; r < 4; ++r) {
        float dist = fmaxf(qnr[r] + knc - 2.f * acc[nt][r], 0.f);
        macc[nt][r] += __expf(__expf(-sc * dist)) * invl[r];
      }
    }
  }
#pragma unroll
  for (int nt = 0; nt < 4; ++nt)
#pragma unroll
    for (int r = 0; r < 4; ++r)
      out1[(size_t)(iw0 + hi * 4 + r) * L_SEQ + j0 + nt * 16 + c] =
          macc[nt][r] * (1.f / 12.f);
}

// ---- launch -------------------------------------------------------------

extern "C" void kernel_launch(void* const* d_in, const int* in_sizes, int n_in,
                              void* d_out, int out_size, void* d_ws, size_t ws_size,
                              hipStream_t stream) {
  const float* x = (const float*)d_in[0];
  const float* Wq = (const float*)d_in[1];
  const float* bq = (const float*)d_in[2];
  const float* Wk = (const float*)d_in[3];
  const float* bk = (const float*)d_in[4];
  const float* Wv = (const float*)d_in[5];
  const float* bv = (const float*)d_in[6];
  const float* Wo = (const float*)d_in[7];
  const float* bo = (const float*)d_in[8];
  const float* theta = (const float*)d_in[9];

  // workspace layout (~20 MB)
  bf16_t* x_bf = (bf16_t*)d_ws;
  bf16_t* Wq_bf = x_bf + (size_t)L_SEQ * DIM;
  bf16_t* Wk_bf = Wq_bf + (size_t)DIM * DIM;
  bf16_t* Wv_bf = Wk_bf + (size_t)DIM * DIM;
  bf16_t* Wo_bf = Wv_bf + (size_t)DIM * DIM;
  bf16_t* q_bf = Wo_bf + (size_t)DIM * DIM;
  bf16_t* k_bf = q_bf + (size_t)NH * L_SEQ * DKH;
  bf16_t* vt_bf = k_bf + (size_t)NH * L_SEQ * DKH;
  bf16_t* ctx_bf = vt_bf + (size_t)NH * L_SEQ * DKH;
  float* qn = (float*)(ctx_bf + (size_t)L_SEQ * DIM);
  float* kn = qn + NH * L_SEQ;
  float* den = kn + NH * L_SEQ;
  float* dmax = den + NH * L_SEQ;
  float* blockmax = dmax + 64;          // NH * JSPLIT * 32 = 1536

  float* out0 = (float*)d_out;
  float* out1 = out0 + (size_t)L_SEQ * DIM;

  cast_x<<<(L_SEQ * DIM / 4 + 255) / 256, 256, 0, stream>>>(x, x_bf, L_SEQ * DIM / 4);
  cast_w4<<<dim3((DIM * DIM / 4 + 255) / 256, 4), 256, 0, stream>>>(
      Wq, Wk, Wv, Wo, Wq_bf, Wk_bf, Wv_bf, Wo_bf, DIM * DIM / 4);

  dim3 gproj(DIM / 64, L_SEQ / 64);
  gemm_nt<0><<<gproj, 256, 0, stream>>>(x_bf, Wq_bf, bq, q_bf, qn, L_SEQ, DIM, DIM);
  gemm_nt<0><<<gproj, 256, 0, stream>>>(x_bf, Wk_bf, bk, k_bf, kn, L_SEQ, DIM, DIM);
  gemm_nt<1><<<gproj, 256, 0, stream>>>(x_bf, Wv_bf, bv, vt_bf, nullptr, L_SEQ, DIM, DIM);

  maxdist<<<dim3(L_SEQ / 64, JSPLIT, NH), 256, 0, stream>>>(q_bf, k_bf, qn, kn, blockmax);
  reduce_dmax<<<NH, 128, 0, stream>>>(blockmax, dmax);
  fusedctx<<<dim3(L_SEQ / 64, NH), 512, 0, stream>>>(q_bf, k_bf, vt_bf, qn, kn, dmax,
                                                     theta, den, ctx_bf);
  attnmean<<<dim3(L_SEQ / 64, L_SEQ / 64), 256, 0, stream>>>(q_bf, k_bf, qn, kn, dmax,
                                                             theta, den, out1);
  gemm_nt<2><<<gproj, 256, 0, stream>>>(ctx_bf, Wo_bf, bo, out0, nullptr, L_SEQ, DIM, DIM);
}

// Round 4
// 139.511 us; speedup vs baseline: 2.3527x; 2.3527x over previous
//
#include <hip/hip_runtime.h>
#include <hip/hip_bf16.h>

// Distance-kernel attention, B=1, L=2048, D=768, H=12, dk=64.
// out0 [L,D] fp32 = context @ Wo^T + bo ; out1 [L,L] fp32 = mean_h attn_weights.
// All matmuls via mfma_f32_16x16x32_bf16 in "NT" form (both operands K-contiguous,
// identical lane->k mapping on A and B => result independent of HW K-permutation).
// Structure: LDS-staged tiles (r2-proven), with register-prefetch staging
// (load t+1 into regs while computing t) to hide global latency, and the
// fused denominator+context pass split across 2 j-chunks for occupancy.

typedef __bf16 bf16_t;
typedef bf16_t bf16x8 __attribute__((ext_vector_type(8)));
typedef float f32x4 __attribute__((ext_vector_type(4)));

#define L_SEQ 2048
#define DIM 768
#define NH 12
#define DKH 64
#define JSPLIT 4   // j-chunks in maxdist pass
#define LOG2E 1.44269504f

__device__ __forceinline__ f32x4 mfma16(bf16x8 a, bf16x8 b, f32x4 c_) {
  return __builtin_amdgcn_mfma_f32_16x16x32_bf16(a, b, c_, 0, 0, 0);
}

// ---- tile staging: load (global->regs) / write (regs->LDS) --------------

struct Tile2 { bf16x8 r[2]; };

__device__ __forceinline__ void tile_load(const bf16_t* __restrict__ src, int stride,
                                          Tile2& t_, int tid) {
#pragma unroll
  for (int c = 0; c < 2; ++c) {
    int chunk = tid + c * 256;
    t_.r[c] = *(const bf16x8*)&src[(size_t)(chunk >> 3) * stride + (chunk & 7) * 8];
  }
}

__device__ __forceinline__ void tile_write(bf16_t (*dst)[72], const Tile2& t_, int tid) {
#pragma unroll
  for (int c = 0; c < 2; ++c) {
    int chunk = tid + c * 256;
    *(bf16x8*)&dst[chunk >> 3][(chunk & 7) * 8] = t_.r[c];
  }
}

// 64x64 = A(64xK=64) * B(64xK=64)^T, per-wave 16x64 strip.
// acc[nt][r]: row m = wid*16 + (lane>>4)*4 + r, col n = nt*16 + (lane&15).
__device__ __forceinline__ void mfma_nt64(bf16_t (*As)[72], bf16_t (*Bs)[72],
                                          int wid, int lane, f32x4 acc[4]) {
#pragma unroll
  for (int ks = 0; ks < 2; ++ks) {
    bf16x8 a = *(const bf16x8*)&As[wid * 16 + (lane & 15)][ks * 32 + (lane >> 4) * 8];
#pragma unroll
    for (int nt = 0; nt < 4; ++nt) {
      bf16x8 b = *(const bf16x8*)&Bs[nt * 16 + (lane & 15)][ks * 32 + (lane >> 4) * 8];
      acc[nt] = mfma16(a, b, acc[nt]);
    }
  }
}

// ---- casts ---------------------------------------------------------------

__global__ void cast_x(const float* __restrict__ in, bf16_t* __restrict__ out, int n4) {
  int i = blockIdx.x * 256 + threadIdx.x;
  if (i >= n4) return;
  float4 v = ((const float4*)in)[i];
  bf16_t* o = out + (size_t)i * 4;
  o[0] = (bf16_t)v.x; o[1] = (bf16_t)v.y; o[2] = (bf16_t)v.z; o[3] = (bf16_t)v.w;
}

__global__ void cast_w4(const float* __restrict__ w0, const float* __restrict__ w1,
                        const float* __restrict__ w2, const float* __restrict__ w3,
                        bf16_t* __restrict__ o0, bf16_t* __restrict__ o1,
                        bf16_t* __restrict__ o2, bf16_t* __restrict__ o3, int n4) {
  int i = blockIdx.x * 256 + threadIdx.x;
  if (i >= n4) return;
  const float* in = blockIdx.y == 0 ? w0 : blockIdx.y == 1 ? w1 : blockIdx.y == 2 ? w2 : w3;
  bf16_t* out = blockIdx.y == 0 ? o0 : blockIdx.y == 1 ? o1 : blockIdx.y == 2 ? o2 : o3;
  float4 v = ((const float4*)in)[i];
  bf16_t* o = out + (size_t)i * 4;
  o[0] = (bf16_t)v.x; o[1] = (bf16_t)v.y; o[2] = (bf16_t)v.z; o[3] = (bf16_t)v.w;
}

// ---- projections ---------------------------------------------------------

// QKV merged: grid (12, 32, 3). z=0: q (head-split + qn), z=1: k (+kn), z=2: v (transposed).
__global__ __launch_bounds__(256) void gemm_qkv(const bf16_t* __restrict__ x,
                                                const bf16_t* __restrict__ Bq,
                                                const bf16_t* __restrict__ Bk,
                                                const bf16_t* __restrict__ Bv,
                                                const float* __restrict__ bq,
                                                const float* __restrict__ bk,
                                                const float* __restrict__ bv,
                                                bf16_t* __restrict__ qo,
                                                bf16_t* __restrict__ ko,
                                                bf16_t* __restrict__ vto,
                                                float* __restrict__ qn,
                                                float* __restrict__ kn) {
  __shared__ bf16_t As[2][64][72];
  __shared__ bf16_t Bs[2][64][72];
  const int z = blockIdx.z;
  const bf16_t* B = z == 0 ? Bq : z == 1 ? Bk : Bv;
  const float* bias = z == 0 ? bq : z == 1 ? bk : bv;
  const int tid = threadIdx.x, wid = tid >> 6, lane = tid & 63;
  const int c = lane & 15, hi = lane >> 4;
  const int m0 = blockIdx.y * 64, n0 = blockIdx.x * 64;
  Tile2 at, bt;
  tile_load(x + (size_t)m0 * DIM, DIM, at, tid);
  tile_load(B + (size_t)n0 * DIM, DIM, bt, tid);
  f32x4 acc[4] = {};
  for (int kk = 0; kk < 12; ++kk) {
    tile_write(As[kk & 1], at, tid);
    tile_write(Bs[kk & 1], bt, tid);
    __syncthreads();
    if (kk < 11) {
      tile_load(x + (size_t)m0 * DIM + (kk + 1) * 64, DIM, at, tid);
      tile_load(B + (size_t)n0 * DIM + (kk + 1) * 64, DIM, bt, tid);
    }
    mfma_nt64(As[kk & 1], Bs[kk & 1], wid, lane, acc);
    __syncthreads();
  }
  const int r0 = wid * 16 + hi * 4;
  float ss[4] = {0.f, 0.f, 0.f, 0.f};
#pragma unroll
  for (int nt = 0; nt < 4; ++nt) {
    int cc = n0 + nt * 16 + c;
    float bv_ = bias[cc];
    int h = cc >> 6, d = cc & 63;
#pragma unroll
    for (int r = 0; r < 4; ++r) {
      int mm = m0 + r0 + r;
      float val = acc[nt][r] + bv_;
      if (z == 2) {
        vto[(size_t)cc * L_SEQ + mm] = (bf16_t)val;        // vt[h*64+d][m]
      } else {
        bf16_t* out = z == 0 ? qo : ko;
        out[((size_t)h * L_SEQ + mm) * 64 + d] = (bf16_t)val;
        ss[r] = fmaf(val, val, ss[r]);
      }
    }
  }
  if (z < 2) {
#pragma unroll
    for (int s = 1; s < 16; s <<= 1)
#pragma unroll
      for (int r = 0; r < 4; ++r) ss[r] += __shfl_xor(ss[r], s);
    if (c == 0) {
      float* norm = z == 0 ? qn : kn;
      int h = n0 >> 6;
#pragma unroll
      for (int r = 0; r < 4; ++r) norm[h * L_SEQ + m0 + r0 + r] = ss[r];
    }
  }
}

// Output projection: out[m,n] = ctx[m,:] . Wo[n,:] + bo[n], fp32.
__global__ __launch_bounds__(256) void gemm_out(const bf16_t* __restrict__ A,
                                                const bf16_t* __restrict__ B,
                                                const float* __restrict__ bias,
                                                float* __restrict__ out) {
  __shared__ bf16_t As[2][64][72];
  __shared__ bf16_t Bs[2][64][72];
  const int tid = threadIdx.x, wid = tid >> 6, lane = tid & 63;
  const int c = lane & 15, hi = lane >> 4;
  const int m0 = blockIdx.y * 64, n0 = blockIdx.x * 64;
  Tile2 at, bt;
  tile_load(A + (size_t)m0 * DIM, DIM, at, tid);
  tile_load(B + (size_t)n0 * DIM, DIM, bt, tid);
  f32x4 acc[4] = {};
  for (int kk = 0; kk < 12; ++kk) {
    tile_write(As[kk & 1], at, tid);
    tile_write(Bs[kk & 1], bt, tid);
    __syncthreads();
    if (kk < 11) {
      tile_load(A + (size_t)m0 * DIM + (kk + 1) * 64, DIM, at, tid);
      tile_load(B + (size_t)n0 * DIM + (kk + 1) * 64, DIM, bt, tid);
    }
    mfma_nt64(As[kk & 1], Bs[kk & 1], wid, lane, acc);
    __syncthreads();
  }
  const int r0 = wid * 16 + hi * 4;
#pragma unroll
  for (int nt = 0; nt < 4; ++nt) {
    int cc = n0 + nt * 16 + c;
    float bv = bias[cc];
#pragma unroll
    for (int r = 0; r < 4; ++r)
      out[(size_t)(m0 + r0 + r) * DIM + cc] = acc[nt][r] + bv;
  }
}

// ---- pass 1: global max of dist_sq --------------------------------------

__global__ __launch_bounds__(256) void maxdist(const bf16_t* __restrict__ q,
                                               const bf16_t* __restrict__ k,
                                               const float* __restrict__ qn,
                                               const float* __restrict__ kn,
                                               float* __restrict__ blockmax) {
  __shared__ bf16_t Qs[64][72];
  __shared__ bf16_t Ks[64][72];
  __shared__ float wmax[4];
  const int it = blockIdx.x, jc = blockIdx.y, h = blockIdx.z;
  const int i0 = it * 64, jbase = jc * (L_SEQ / JSPLIT);
  const int tid = threadIdx.x, wid = tid >> 6, lane = tid & 63;
  const int c = lane & 15, hi = lane >> 4;
  Tile2 qt, kt;
  tile_load(q + ((size_t)h * L_SEQ + i0) * DKH, DKH, qt, tid);
  tile_write(Qs, qt, tid);
  tile_load(k + ((size_t)h * L_SEQ + jbase) * DKH, DKH, kt, tid);
  const int r0 = wid * 16 + hi * 4;
  float qnr[4];
#pragma unroll
  for (int r = 0; r < 4; ++r) qnr[r] = qn[h * L_SEQ + i0 + r0 + r];
  float m = 0.f;
  const int NT = L_SEQ / 64 / JSPLIT;
  for (int t = 0; t < NT; ++t) {
    tile_write(Ks, kt, tid);
    __syncthreads();
    if (t < NT - 1)
      tile_load(k + ((size_t)h * L_SEQ + jbase + (t + 1) * 64) * DKH, DKH, kt, tid);
    f32x4 acc[4] = {};
    mfma_nt64(Qs, Ks, wid, lane, acc);
#pragma unroll
    for (int nt = 0; nt < 4; ++nt) {
      float knc = kn[h * L_SEQ + jbase + t * 64 + nt * 16 + c];
#pragma unroll
      for (int r = 0; r < 4; ++r)
        m = fmaxf(m, fmaf(-2.f, acc[nt][r], qnr[r] + knc));
    }
    __syncthreads();
  }
#pragma unroll
  for (int s = 1; s < 64; s <<= 1) m = fmaxf(m, __shfl_xor(m, s));
  if (lane == 0) wmax[wid] = m;
  __syncthreads();
  if (tid == 0) {
    float bm = fmaxf(fmaxf(wmax[0], wmax[1]), fmaxf(wmax[2], wmax[3]));
    blockmax[(h * JSPLIT + jc) * (L_SEQ / 64) + it] = fmaxf(bm, 0.f) * (1.f / 64.f);
  }
}

__global__ void reduce_dmax(const float* __restrict__ blockmax, float* __restrict__ dmax) {
  __shared__ float wm[2];
  const int h = blockIdx.x, tid = threadIdx.x, lane = tid & 63, wid = tid >> 6;
  float m = blockmax[h * 128 + tid];
#pragma unroll
  for (int s = 1; s < 64; s <<= 1) m = fmaxf(m, __shfl_xor(m, s));
  if (lane == 0) wm[wid] = m;
  __syncthreads();
  if (tid == 0) dmax[h] = fmaxf(wm[0], wm[1]);
}

// ---- pass 2: partial denominator + partial unnormalized context^T -------
// grid (32 i-tiles, 2 j-chunks, 12 heads). 256 thr, single-buffer LDS, 3 syncs/iter,
// register prefetch for K/V tiles.
__global__ __launch_bounds__(256) void fusedctx_p(const bf16_t* __restrict__ q,
                                                  const bf16_t* __restrict__ k,
                                                  const bf16_t* __restrict__ vt,
                                                  const float* __restrict__ qn,
                                                  const float* __restrict__ kn,
                                                  const float* __restrict__ dmax,
                                                  const float* __restrict__ theta,
                                                  float* __restrict__ denP,
                                                  float* __restrict__ ctxP) {
  __shared__ bf16_t Qs[64][72];
  __shared__ bf16_t Ks[64][72];
  __shared__ bf16_t Vs[64][72];
  __shared__ bf16_t Ws[64][72];
  const int it = blockIdx.x, jc = blockIdx.y, h = blockIdx.z;
  const int i0 = it * 64, jbase = jc * (L_SEQ / 2);
  const int tid = threadIdx.x, wid = tid >> 6, lane = tid & 63;
  const int c = lane & 15, hi = lane >> 4;
  const float sc = __expf(theta[h]) * (1.f / 64.f) / (dmax[h] + 1e-6f);
  const float twosc = 2.f * sc;
  Tile2 qt, kt, vtr;
  tile_load(q + ((size_t)h * L_SEQ + i0) * DKH, DKH, qt, tid);
  tile_write(Qs, qt, tid);
  tile_load(k + ((size_t)h * L_SEQ + jbase) * DKH, DKH, kt, tid);
  tile_load(vt + (size_t)h * DKH * L_SEQ + jbase, L_SEQ, vtr, tid);
  const int r0 = wid * 16 + hi * 4;
  float aq[4];
#pragma unroll
  for (int r = 0; r < 4; ++r) aq[r] = sc * qn[h * L_SEQ + i0 + r0 + r];
  float psum[4] = {0.f, 0.f, 0.f, 0.f};
  f32x4 cacc[4] = {};
  const int NT = L_SEQ / 2 / 64;
  for (int t = 0; t < NT; ++t) {
    tile_write(Ks, kt, tid);
    tile_write(Vs, vtr, tid);
    __syncthreads();
    if (t < NT - 1) {
      tile_load(k + ((size_t)h * L_SEQ + jbase + (t + 1) * 64) * DKH, DKH, kt, tid);
      tile_load(vt + (size_t)h * DKH * L_SEQ + jbase + (t + 1) * 64, L_SEQ, vtr, tid);
    }
    f32x4 acc[4] = {};
    mfma_nt64(Qs, Ks, wid, lane, acc);
#pragma unroll
    for (int nt = 0; nt < 4; ++nt) {
      float bkn = -sc * kn[h * L_SEQ + jbase + t * 64 + nt * 16 + c];
#pragma unroll
      for (int r = 0; r < 4; ++r) {
        float tt = fminf(fmaf(twosc, acc[nt][r], bkn - aq[r]), 0.f);
        float w = __expf(__expf(tt));      // in (1, e]
        psum[r] += w;
        Ws[r0 + r][nt * 16 + c] = (bf16_t)w;
      }
    }
    __syncthreads();
    // ctx^T partial: A = Vs (m=d strip), B = Ws (n=i), k = j
    mfma_nt64(Vs, Ws, wid, lane, cacc);
    __syncthreads();
  }
#pragma unroll
  for (int s = 1; s < 16; s <<= 1)
#pragma unroll
    for (int r = 0; r < 4; ++r) psum[r] += __shfl_xor(psum[r], s);
  if (c == 0)
#pragma unroll
    for (int r = 0; r < 4; ++r)
      denP[(size_t)(h * 2 + jc) * L_SEQ + i0 + r0 + r] = psum[r];
  // cacc[nt][r]: d = r0+r, i_local = nt*16+c. Store [il][d] fp32 (f32x4 over d).
  float* P = ctxP + ((size_t)(h * 2 + jc) * 32 + it) * 4096;
#pragma unroll
  for (int nt = 0; nt < 4; ++nt)
    *(f32x4*)&P[(nt * 16 + c) * 64 + r0] = cacc[nt];
}

// Combine j-half partials: den + normalized bf16 ctx. grid (32, 12), 256 thr.
__global__ __launch_bounds__(256) void ctx_combine(const float* __restrict__ denP,
                                                   const float* __restrict__ ctxP,
                                                   float* __restrict__ den,
                                                   bf16_t* __restrict__ ctx) {
  __shared__ float invL[64];
  const int it = blockIdx.x, h = blockIdx.y, tid = threadIdx.x;
  const int i0 = it * 64;
  if (tid < 64) {
    float d0 = denP[(size_t)(h * 2) * L_SEQ + i0 + tid] +
               denP[(size_t)(h * 2 + 1) * L_SEQ + i0 + tid];
    den[h * L_SEQ + i0 + tid] = d0;
    invL[tid] = 1.f / d0;
  }
  __syncthreads();
  const float* P0 = ctxP + ((size_t)(h * 2) * 32 + it) * 4096;
  const float* P1 = ctxP + ((size_t)(h * 2 + 1) * 32 + it) * 4096;
  const int il = tid >> 2, db = (tid & 3) * 16;
  const float inv = invL[il];
  bf16_t* dst = ctx + (size_t)(i0 + il) * DIM + h * 64 + db;
#pragma unroll
  for (int half = 0; half < 2; ++half) {
    bf16x8 o;
#pragma unroll
    for (int e = 0; e < 2; ++e) {
      f32x4 v0 = *(const f32x4*)&P0[il * 64 + db + half * 8 + e * 4];
      f32x4 v1 = *(const f32x4*)&P1[il * 64 + db + half * 8 + e * 4];
#pragma unroll
      for (int j = 0; j < 4; ++j) o[e * 4 + j] = (bf16_t)((v0[j] + v1[j]) * inv);
    }
    *(bf16x8*)&dst[half * 8] = o;
  }
}

// ---- pass 3: out1 = mean over heads of attn weights ---------------------
// grid (32 j, 32 i). Double-buffered Q/K staging, 1 sync/head.
__global__ __launch_bounds__(256) void attnmean(const bf16_t* __restrict__ q,
                                                const bf16_t* __restrict__ k,
                                                const float* __restrict__ qn,
                                                const float* __restrict__ kn,
                                                const float* __restrict__ dmax,
                                                const float* __restrict__ theta,
                                                const float* __restrict__ den,
                                                float* __restrict__ out1) {
  __shared__ bf16_t Qs[2][64][72];
  __shared__ bf16_t Ks[2][64][72];
  const int i0 = blockIdx.y * 64, j0 = blockIdx.x * 64;
  const int tid = threadIdx.x, wid = tid >> 6, lane = tid & 63;
  const int c = lane & 15, hi = lane >> 4;
  const int r0 = wid * 16 + hi * 4;
  Tile2 qt, kt;
  tile_load(q + (size_t)i0 * DKH, DKH, qt, tid);              // h = 0
  tile_load(k + (size_t)j0 * DKH, DKH, kt, tid);
  float macc[4][4] = {};
  for (int h = 0; h < NH; ++h) {
    tile_write(Qs[h & 1], qt, tid);
    tile_write(Ks[h & 1], kt, tid);
    __syncthreads();
    if (h < NH - 1) {
      tile_load(q + ((size_t)(h + 1) * L_SEQ + i0) * DKH, DKH, qt, tid);
      tile_load(k + ((size_t)(h + 1) * L_SEQ + j0) * DKH, DKH, kt, tid);
    }
    const float sc = __expf(theta[h]) * (1.f / 64.f) / (dmax[h] + 1e-6f);
    const float twosc = 2.f * sc;
    f32x4 acc[4] = {};
    mfma_nt64(Qs[h & 1], Ks[h & 1], wid, lane, acc);
    float aq[4], invl[4];
#pragma unroll
    for (int r = 0; r < 4; ++r) {
      aq[r] = sc * qn[h * L_SEQ + i0 + r0 + r];
      invl[r] = 1.f / den[h * L_SEQ + i0 + r0 + r];
    }
#pragma unroll
    for (int nt = 0; nt < 4; ++nt) {
      float bkn = -sc * kn[h * L_SEQ + j0 + nt * 16 + c];
#pragma unroll
      for (int r = 0; r < 4; ++r) {
        float tt = fminf(fmaf(twosc, acc[nt][r], bkn - aq[r]), 0.f);
        float w = __expf(__expf(tt));
        macc[nt][r] = fmaf(w, invl[r], macc[nt][r]);
      }
    }
  }
#pragma unroll
  for (int nt = 0; nt < 4; ++nt)
#pragma unroll
    for (int r = 0; r < 4; ++r)
      out1[(size_t)(i0 + r0 + r) * L_SEQ + j0 + nt * 16 + c] =
          macc[nt][r] * (1.f / 12.f);
}

// ---- launch -------------------------------------------------------------

extern "C" void kernel_launch(void* const* d_in, const int* in_sizes, int n_in,
                              void* d_out, int out_size, void* d_ws, size_t ws_size,
                              hipStream_t stream) {
  const float* x = (const float*)d_in[0];
  const float* Wq = (const float*)d_in[1];
  const float* bq = (const float*)d_in[2];
  const float* Wk = (const float*)d_in[3];
  const float* bk = (const float*)d_in[4];
  const float* Wv = (const float*)d_in[5];
  const float* bv = (const float*)d_in[6];
  const float* Wo = (const float*)d_in[7];
  const float* bo = (const float*)d_in[8];
  const float* theta = (const float*)d_in[9];

  // workspace layout (~34 MB)
  bf16_t* x_bf = (bf16_t*)d_ws;
  bf16_t* Wq_bf = x_bf + (size_t)L_SEQ * DIM;
  bf16_t* Wk_bf = Wq_bf + (size_t)DIM * DIM;
  bf16_t* Wv_bf = Wk_bf + (size_t)DIM * DIM;
  bf16_t* Wo_bf = Wv_bf + (size_t)DIM * DIM;
  bf16_t* q_bf = Wo_bf + (size_t)DIM * DIM;
  bf16_t* k_bf = q_bf + (size_t)NH * L_SEQ * DKH;
  bf16_t* vt_bf = k_bf + (size_t)NH * L_SEQ * DKH;
  bf16_t* ctx_bf = vt_bf + (size_t)NH * L_SEQ * DKH;
  float* qn = (float*)(ctx_bf + (size_t)L_SEQ * DIM);
  float* kn = qn + NH * L_SEQ;
  float* den = kn + NH * L_SEQ;
  float* dmax = den + NH * L_SEQ;
  float* blockmax = dmax + 64;                     // 1536
  float* denP = blockmax + 2048;                   // 24 * 2048
  float* ctxP = denP + 24 * L_SEQ;                 // 24 * 32 * 4096 fp32 (~12.6 MB)

  float* out0 = (float*)d_out;
  float* out1 = out0 + (size_t)L_SEQ * DIM;

  cast_x<<<(L_SEQ * DIM / 4 + 255) / 256, 256, 0, stream>>>(x, x_bf, L_SEQ * DIM / 4);
  cast_w4<<<dim3((DIM * DIM / 4 + 255) / 256, 4), 256, 0, stream>>>(
      Wq, Wk, Wv, Wo, Wq_bf, Wk_bf, Wv_bf, Wo_bf, DIM * DIM / 4);

  gemm_qkv<<<dim3(DIM / 64, L_SEQ / 64, 3), 256, 0, stream>>>(
      x_bf, Wq_bf, Wk_bf, Wv_bf, bq, bk, bv, q_bf, k_bf, vt_bf, qn, kn);

  maxdist<<<dim3(L_SEQ / 64, JSPLIT, NH), 256, 0, stream>>>(q_bf, k_bf, qn, kn, blockmax);
  reduce_dmax<<<NH, 128, 0, stream>>>(blockmax, dmax);

  fusedctx_p<<<dim3(L_SEQ / 64, 2, NH), 256, 0, stream>>>(q_bf, k_bf, vt_bf, qn, kn,
                                                          dmax, theta, denP, ctxP);
  ctx_combine<<<dim3(L_SEQ / 64, NH), 256, 0, stream>>>(denP, ctxP, den, ctx_bf);

  attnmean<<<dim3(L_SEQ / 64, L_SEQ / 64), 256, 0, stream>>>(q_bf, k_bf, qn, kn, dmax,
                                                             theta, den, out1);
  gemm_out<<<dim3(DIM / 64, L_SEQ / 64), 256, 0, stream>>>(ctx_bf, Wo_bf, bo, out0);
}